// Round 4
// baseline (679.128 us; speedup 1.0000x reference)
//
#include <hip/hip_runtime.h>
#include <hip/hip_bf16.h>
#include <math.h>

// Shapes: B=1, S=512, N=384, c_m=64, c_z=128, H=8, c=32  (HC = 256)
//
// Pipeline:
//  k0     : W4 -> W4t[d][hc] bf16; W1|W3 -> W13t[n][k] bf16 (n=0..511)
//  k1     : LN(m) -> bf16 LDS; MFMA x(W1|W3); D^T epilogue writes
//           v_tg[s][hc][j] and g_t[s][hc][j] = sigmoid  (hc-major!)
//  k2     : b = LN(z)@W2 -> w_buf[h][i][j] fp32
//  k3a/m/b: softmax over i -> w_bf[h][i][j] bf16
//  k4     : barrier-free MFMA: wave owns 32i x 32c; A,B frags direct from
//           global (L1/L2); gate; per-wave o_h LDS; fused @W4 rank-32 updates.

typedef __attribute__((ext_vector_type(8))) short bf16x8;   // 8 bf16 = 4 VGPRs
typedef __attribute__((ext_vector_type(4))) float f32x4;

__device__ __forceinline__ short f2bfs(float x) {
    __hip_bfloat16 b = __float2bfloat16(x);
    return *(short*)&b;
}

// ---------------------------------------------------------------------------
__global__ __launch_bounds__(256) void k0_prep(
    const float* __restrict__ W4, const float* __restrict__ W1,
    const float* __restrict__ W3,
    __hip_bfloat16* __restrict__ W4t, __hip_bfloat16* __restrict__ W13t)
{
    int idx = blockIdx.x * 256 + threadIdx.x;   // 49152 total
    if (idx < 16384) {
        int d = idx >> 8, k = idx & 255;
        W4t[idx] = __float2bfloat16(W4[k * 64 + d]);     // W4t[d][hc]
    } else {
        int j = idx - 16384;                    // 0..32767
        int n = j >> 6, k = j & 63;
        float w = (n < 256) ? W1[k * 256 + n] : W3[k * 256 + (n - 256)];
        W13t[j] = __float2bfloat16(w);                   // W13t[n][k]
    }
}

// ---------------------------------------------------------------------------
// k1: 64 token-rows per block; LN -> bf16 LDS; MFMA vs W13t; grid 3072.
__global__ __launch_bounds__(256, 4) void k1_ln_mv(
    const float* __restrict__ m_si,
    const float* __restrict__ gamma_m, const float* __restrict__ beta_m,
    const __hip_bfloat16* __restrict__ W13t,   // [512][64]
    __hip_bfloat16* __restrict__ v_tg,         // [512][256][384] (hc-major)
    __hip_bfloat16* __restrict__ g_t)          // [512][256][384]
{
    __shared__ short mh[64 * 72];              // 9216 B, stride 72 (sb step 9)
    const int bx = blockIdx.x;
    const int s = bx / 6, j0 = (bx % 6) * 64;
    const int tid = threadIdx.x, lane = tid & 63, wv = tid >> 6;
    const int col = lane & 15, quad = lane >> 4;

    // phase 1: LN of 64 rows (wave wv: rows wv*16 .. wv*16+15), bf16 to LDS
    const float gm = gamma_m[lane], bm = beta_m[lane];
    const float* mbase = m_si + (size_t)(s * 384 + j0) * 64;
    #pragma unroll 4
    for (int rr = 0; rr < 16; rr++) {
        int r = wv * 16 + rr;
        float x = mbase[r * 64 + lane];
        float s1 = x, s2 = x * x;
        #pragma unroll
        for (int off = 32; off > 0; off >>= 1) {
            s1 += __shfl_xor(s1, off, 64);
            s2 += __shfl_xor(s2, off, 64);
        }
        float mu  = s1 * (1.0f / 64.0f);
        float var = s2 * (1.0f / 64.0f) - mu * mu;
        float rs  = rsqrtf(var + 1e-5f);
        mh[r * 72 + lane] = f2bfs((x - mu) * rs * gm + bm);
    }
    __syncthreads();

    // phase 2: n-tiles nt = wv + 4*nn.  D^T = W13t_tile @ mh^T:
    //   A[m=hc][k] = W13t[(nt*16+col)*64 + quad*8 + ...]
    //   B[k][n=j]  = mh[(it*16+col)*72 + quad*8 + ...]
    //   D: lane(quad,col) reg: hc = nt*16+quad*4+reg, j = j0+it*16+col
    short* vdst = (short*)v_tg + (size_t)s * 98304 + j0 + col;
    short* gdst = (short*)g_t  + (size_t)s * 98304 + j0 + col;
    #pragma unroll 1
    for (int nn = 0; nn < 8; nn++) {
        int nt = wv + nn * 4;
        const short* wa = (const short*)W13t + (nt * 16 + col) * 64 + quad * 8;
        bf16x8 A0 = *(const bf16x8*)(wa);
        bf16x8 A1 = *(const bf16x8*)(wa + 32);
        const bool isv = nt < 16;
        const int hcb = (isv ? nt : nt - 16) * 16 + quad * 4;
        short* dst = isv ? vdst : gdst;
        #pragma unroll
        for (int it = 0; it < 4; it++) {
            const short* mrow = &mh[(it * 16 + col) * 72 + quad * 8];
            bf16x8 B0 = *(const bf16x8*)(mrow);
            bf16x8 B1 = *(const bf16x8*)(mrow + 32);
            f32x4 acc = {0.f, 0.f, 0.f, 0.f};
            acc = __builtin_amdgcn_mfma_f32_16x16x32_bf16(A0, B0, acc, 0, 0, 0);
            acc = __builtin_amdgcn_mfma_f32_16x16x32_bf16(A1, B1, acc, 0, 0, 0);
            if (isv) {
                #pragma unroll
                for (int reg = 0; reg < 4; reg++)
                    dst[(size_t)(hcb + reg) * 384 + it * 16] = f2bfs(acc[reg]);
            } else {
                #pragma unroll
                for (int reg = 0; reg < 4; reg++) {
                    float g = 1.0f / (1.0f + __expf(-acc[reg]));
                    dst[(size_t)(hcb + reg) * 384 + it * 16] = f2bfs(g);
                }
            }
        }
    }
}

// ---------------------------------------------------------------------------
// k2: 64 rows/block, 4 waves, one wave per row step. grid = 2304.
__global__ __launch_bounds__(256) void k2_ln_z(
    const float* __restrict__ z,
    const float* __restrict__ gamma_z, const float* __restrict__ beta_z,
    const float* __restrict__ W2, float* __restrict__ b_buf)
{
    const int tid = threadIdx.x;
    const int lane = tid & 63, wv = tid >> 6;
    const int R0 = blockIdx.x * 64;
    __shared__ float part[64][9];

    float2 g2 = *(const float2*)&gamma_z[lane * 2];
    float2 be2 = *(const float2*)&beta_z[lane * 2];
    float4 w2a = *(const float4*)&W2[lane * 16];
    float4 w2b = *(const float4*)&W2[lane * 16 + 4];
    float4 w2c = *(const float4*)&W2[lane * 16 + 8];
    float4 w2d = *(const float4*)&W2[lane * 16 + 12];

    const bool hi4 = (lane & 4) != 0;
    const bool hi2 = (lane & 2) != 0;
    const bool hi1 = (lane & 1) != 0;

    float2 zx = *(const float2*)&z[(size_t)(R0 + wv * 16) * 128 + lane * 2];
    #pragma unroll 1
    for (int rr = 0; rr < 16; rr++) {
        const int rl = wv * 16 + rr;
        float x0 = zx.x, x1 = zx.y;
        if (rr < 15)
            zx = *(const float2*)&z[(size_t)(R0 + rl + 1) * 128 + lane * 2];

        float s1 = x0 + x1, s2 = x0 * x0 + x1 * x1;
        #pragma unroll
        for (int off = 32; off > 0; off >>= 1) {
            s1 += __shfl_xor(s1, off, 64);
            s2 += __shfl_xor(s2, off, 64);
        }
        float mu  = s1 * (1.0f / 128.0f);
        float var = s2 * (1.0f / 128.0f) - mu * mu;
        float rs  = rsqrtf(var + 1e-5f);
        float mh0 = (x0 - mu) * rs * g2.x + be2.x;
        float mh1 = (x1 - mu) * rs * g2.y + be2.y;

        float p[8];
        p[0] = fmaf(mh0, w2a.x, mh1 * w2c.x);
        p[1] = fmaf(mh0, w2a.y, mh1 * w2c.y);
        p[2] = fmaf(mh0, w2a.z, mh1 * w2c.z);
        p[3] = fmaf(mh0, w2a.w, mh1 * w2c.w);
        p[4] = fmaf(mh0, w2b.x, mh1 * w2d.x);
        p[5] = fmaf(mh0, w2b.y, mh1 * w2d.y);
        p[6] = fmaf(mh0, w2b.z, mh1 * w2d.z);
        p[7] = fmaf(mh0, w2b.w, mh1 * w2d.w);

        float t[4];
        #pragma unroll
        for (int k = 0; k < 4; k++) {
            float keep = hi4 ? p[k + 4] : p[k];
            float send = hi4 ? p[k] : p[k + 4];
            t[k] = keep + __shfl_xor(send, 4, 64);
        }
        float u[2];
        #pragma unroll
        for (int k = 0; k < 2; k++) {
            float keep = hi2 ? t[k + 2] : t[k];
            float send = hi2 ? t[k] : t[k + 2];
            u[k] = keep + __shfl_xor(send, 2, 64);
        }
        float vsum;
        {
            float keep = hi1 ? u[1] : u[0];
            float send = hi1 ? u[0] : u[1];
            vsum = keep + __shfl_xor(send, 1, 64);
        }
        vsum += __shfl_xor(vsum, 8, 64);
        vsum += __shfl_xor(vsum, 16, 64);
        vsum += __shfl_xor(vsum, 32, 64);
        if (lane < 8) part[rl][lane] = vsum;
    }
    __syncthreads();
    {
        int h0 = tid >> 6, rl = tid & 63;
        b_buf[(size_t)h0 * 147456 + R0 + rl]       = part[rl][h0];
        b_buf[(size_t)(h0 + 4) * 147456 + R0 + rl] = part[rl][h0 + 4];
    }
}

// ---------------------------------------------------------------------------
__global__ __launch_bounds__(128) void k3a_part(
    const float* __restrict__ w_buf, float* __restrict__ pm, float* __restrict__ pl)
{
    const int h = blockIdx.x / 24, ic = blockIdx.x % 24;
    const int i0 = ic * 16;
    const int tid = threadIdx.x;
    const float* base = w_buf + ((size_t)h * 384 + i0) * 384;

    float m0 = -INFINITY, m1 = -INFINITY, m2 = -INFINITY;
    float l0 = 0.f, l1 = 0.f, l2 = 0.f;
    #pragma unroll 4
    for (int ii = 0; ii < 16; ii++) {
        float x0 = base[ii * 384 + tid];
        float x1 = base[ii * 384 + tid + 128];
        float x2 = base[ii * 384 + tid + 256];
        float n0 = fmaxf(m0, x0);
        l0 = l0 * __expf(m0 - n0) + __expf(x0 - n0); m0 = n0;
        float n1 = fmaxf(m1, x1);
        l1 = l1 * __expf(m1 - n1) + __expf(x1 - n1); m1 = n1;
        float n2 = fmaxf(m2, x2);
        l2 = l2 * __expf(m2 - n2) + __expf(x2 - n2); m2 = n2;
    }
    float* pmb = pm + ((size_t)h * 24 + ic) * 384;
    float* plb = pl + ((size_t)h * 24 + ic) * 384;
    pmb[tid]       = m0;  plb[tid]       = l0;
    pmb[tid + 128] = m1;  plb[tid + 128] = l1;
    pmb[tid + 256] = m2;  plb[tid + 256] = l2;
}

__global__ __launch_bounds__(384) void k3m_comb(
    const float* __restrict__ pm, const float* __restrict__ pl,
    float* __restrict__ Mf, float* __restrict__ invLf)
{
    const int h = blockIdx.x, j = threadIdx.x;
    float M = -INFINITY, L = 0.f;
    #pragma unroll 4
    for (int ic = 0; ic < 24; ic++) {
        float m = pm[((size_t)h * 24 + ic) * 384 + j];
        float l = pl[((size_t)h * 24 + ic) * 384 + j];
        float nM = fmaxf(M, m);
        L = L * __expf(M - nM) + l * __expf(m - nM);
        M = nM;
    }
    Mf[h * 384 + j] = M;
    invLf[h * 384 + j] = 1.0f / L;
}

__global__ __launch_bounds__(128) void k3b_write(
    const float* __restrict__ w_buf, const float* __restrict__ Mf,
    const float* __restrict__ invLf, __hip_bfloat16* __restrict__ w_bf)
{
    const int h = blockIdx.x / 24, ic = blockIdx.x % 24;
    const int i0 = ic * 16;
    const int tid = threadIdx.x;
    const float* base = w_buf + ((size_t)h * 384 + i0) * 384;
    __hip_bfloat16* ob = w_bf + ((size_t)h * 384 + i0) * 384;

    float M0 = Mf[h * 384 + tid],       iL0 = invLf[h * 384 + tid];
    float M1 = Mf[h * 384 + tid + 128], iL1 = invLf[h * 384 + tid + 128];
    float M2 = Mf[h * 384 + tid + 256], iL2 = invLf[h * 384 + tid + 256];
    #pragma unroll 4
    for (int ii = 0; ii < 16; ii++) {
        float x0 = base[ii * 384 + tid];
        float x1 = base[ii * 384 + tid + 128];
        float x2 = base[ii * 384 + tid + 256];
        ob[ii * 384 + tid]       = __float2bfloat16(__expf(x0 - M0) * iL0);
        ob[ii * 384 + tid + 128] = __float2bfloat16(__expf(x1 - M1) * iL1);
        ob[ii * 384 + tid + 256] = __float2bfloat16(__expf(x2 - M2) * iL2);
    }
}

// ---------------------------------------------------------------------------
// k4: barrier-free. grid = 512*3 = 1536 blocks; wave owns 32 i x 32 c.
#define OHSTR 40    // o_h row stride (shorts); 80 B -> sb step 5 (odd)

__global__ __launch_bounds__(256, 4) void k4_mfma(
    const __hip_bfloat16* __restrict__ w_bf,   // [8][384][384]
    const __hip_bfloat16* __restrict__ v_tg,   // [512][256][384]
    const __hip_bfloat16* __restrict__ g_t,    // [512][256][384]
    const __hip_bfloat16* __restrict__ W4t,    // [64][256]
    float* __restrict__ out)                   // [512][384][64]
{
    __shared__ short o_h[4][32 * OHSTR];       // 10240 B, per-wave private
    const int bx = blockIdx.x;
    const int s = bx / 3, i0 = (bx % 3) * 128;
    const int tid = threadIdx.x, lane = tid & 63, wv = tid >> 6;
    const int col = lane & 15, quad = lane >> 4;
    const int ib = i0 + wv * 32;               // wave's 32 i-rows: ib..ib+31

    const short* wrow0 = (const short*)w_bf + (size_t)(ib + col) * 384 + quad * 8;
    const short* vbase = (const short*)v_tg + (size_t)s * 98304 + col * 384 + quad * 8;
    const short* gbase = (const short*)g_t + (size_t)s * 98304;
    const short* w4b   = (const short*)W4t + col * 256 + quad * 8;
    short* oh = o_h[wv];

    f32x4 acc2[2][4];
    #pragma unroll
    for (int it = 0; it < 2; it++)
        #pragma unroll
        for (int dt = 0; dt < 4; dt++) acc2[it][dt] = (f32x4){0.f, 0.f, 0.f, 0.f};

    #pragma unroll 1
    for (int h = 0; h < 8; h++) {
        const short* wA0 = wrow0 + (size_t)h * 147456;
        const short* wA1 = wA0 + 16 * 384;
        const short* vB  = vbase + h * 12288;

        f32x4 e00 = {0.f,0.f,0.f,0.f}, e01 = {0.f,0.f,0.f,0.f};
        f32x4 e10 = {0.f,0.f,0.f,0.f}, e11 = {0.f,0.f,0.f,0.f};
        #pragma unroll
        for (int ks = 0; ks < 12; ks++) {
            int k0 = ks * 32;
            bf16x8 a0 = *(const bf16x8*)(wA0 + k0);
            bf16x8 a1 = *(const bf16x8*)(wA1 + k0);
            bf16x8 b0 = *(const bf16x8*)(vB + k0);
            bf16x8 b1 = *(const bf16x8*)(vB + 16 * 384 + k0);
            e00 = __builtin_amdgcn_mfma_f32_16x16x32_bf16(a0, b0, e00, 0, 0, 0);
            e01 = __builtin_amdgcn_mfma_f32_16x16x32_bf16(a0, b1, e01, 0, 0, 0);
            e10 = __builtin_amdgcn_mfma_f32_16x16x32_bf16(a1, b0, e10, 0, 0, 0);
            e11 = __builtin_amdgcn_mfma_f32_16x16x32_bf16(a1, b1, e11, 0, 0, 0);
        }

        // gate + park in per-wave o_h (i_local x c32)
        const short* g0 = gbase + (size_t)(h * 32 + col) * 384 + ib;
        const short* g1 = gbase + (size_t)(h * 32 + 16 + col) * 384 + ib;
        #pragma unroll
        for (int reg = 0; reg < 4; reg++) {
            int il = quad * 4 + reg;
            float ga = __bfloat162float(*(const __hip_bfloat16*)&g0[il]);
            float gb = __bfloat162float(*(const __hip_bfloat16*)&g1[il]);
            float gc = __bfloat162float(*(const __hip_bfloat16*)&g0[16 + il]);
            float gd = __bfloat162float(*(const __hip_bfloat16*)&g1[16 + il]);
            oh[il * OHSTR + col]             = f2bfs(e00[reg] * ga);
            oh[il * OHSTR + 16 + col]        = f2bfs(e01[reg] * gb);
            oh[(16 + il) * OHSTR + col]      = f2bfs(e10[reg] * gc);
            oh[(16 + il) * OHSTR + 16 + col] = f2bfs(e11[reg] * gd);
        }

        // fused @W4: rank-32 update for this h (same-wave LDS, no barrier)
        bf16x8 a2_0 = *(const bf16x8*)&oh[col * OHSTR + quad * 8];
        bf16x8 a2_1 = *(const bf16x8*)&oh[(16 + col) * OHSTR + quad * 8];
        #pragma unroll
        for (int dt = 0; dt < 4; dt++) {
            bf16x8 b = *(const bf16x8*)(w4b + dt * 4096 + h * 32);
            acc2[0][dt] = __builtin_amdgcn_mfma_f32_16x16x32_bf16(a2_0, b, acc2[0][dt], 0, 0, 0);
            acc2[1][dt] = __builtin_amdgcn_mfma_f32_16x16x32_bf16(a2_1, b, acc2[1][dt], 0, 0, 0);
        }
    }

    // out: D layout rows = i, cols = d; coalesced 64 B per quad-row
    #pragma unroll
    for (int it = 0; it < 2; it++) {
        float* ob = out + (size_t)(s * 384 + ib + it * 16 + quad * 4) * 64;
        #pragma unroll
        for (int dt = 0; dt < 4; dt++)
            #pragma unroll
            for (int reg = 0; reg < 4; reg++)
                ob[reg * 64 + dt * 16 + col] = acc2[it][dt][reg];
    }
}

// ---------------------------------------------------------------------------
extern "C" void kernel_launch(void* const* d_in, const int* in_sizes, int n_in,
                              void* d_out, int out_size, void* d_ws, size_t ws_size,
                              hipStream_t stream)
{
    const float* m_si    = (const float*)d_in[0];
    const float* z_ij    = (const float*)d_in[1];
    const float* gamma_m = (const float*)d_in[2];
    const float* beta_m  = (const float*)d_in[3];
    const float* W1      = (const float*)d_in[4];
    const float* gamma_z = (const float*)d_in[5];
    const float* beta_z  = (const float*)d_in[6];
    const float* W2      = (const float*)d_in[7];
    const float* W3      = (const float*)d_in[8];
    const float* W4      = (const float*)d_in[9];
    float* out = (float*)d_out;

    // ws layout (~209.1 MB):
    char* ws = (char*)d_ws;
    __hip_bfloat16* g_t  = (__hip_bfloat16*)ws;                 // 100663296
    __hip_bfloat16* v_tg = (__hip_bfloat16*)(ws + 100663296);   // 100663296
    float*          w_buf = (float*)(ws + 201326592);           // 4718592
    __hip_bfloat16* w_bf = (__hip_bfloat16*)(ws + 206045184);   // 2359296
    __hip_bfloat16* W4t  = (__hip_bfloat16*)(ws + 208404480);   // 32768
    float* pm    = (float*)(ws + 208437248);                    // 294912
    float* pl    = (float*)(ws + 208732160);                    // 294912
    float* Mf    = (float*)(ws + 209027072);                    // 12288
    float* invLf = (float*)(ws + 209039360);                    // 12288
    __hip_bfloat16* W13t = (__hip_bfloat16*)(ws + 209051648);   // 65536

    k0_prep  <<<192,   256, 0, stream>>>(W4, W1, W3, W4t, W13t);
    k1_ln_mv <<<3072,  256, 0, stream>>>(m_si, gamma_m, beta_m, W13t, v_tg, g_t);
    k2_ln_z  <<<2304,  256, 0, stream>>>(z_ij, gamma_z, beta_z, W2, w_buf);
    k3a_part <<<192,   128, 0, stream>>>(w_buf, pm, pl);
    k3m_comb <<<8,     384, 0, stream>>>(pm, pl, Mf, invLf);
    k3b_write<<<192,   128, 0, stream>>>(w_buf, Mf, invLf, w_bf);
    k4_mfma  <<<1536,  256, 0, stream>>>(w_bf, v_tg, g_t, W4t, out);
}